// Round 2
// baseline (575.807 us; speedup 1.0000x reference)
//
#include <hip/hip_runtime.h>
#include <cstdint>
#include <cstddef>

typedef unsigned int u32;
typedef unsigned short u16;

#define NB 64
#define DIN 512
#define UNITS 1024
#define TOPICS 20
#define VOCAB 32000

// out element offset of next_state within d_out (word_prob first, then next_state)
#define NS_OFF ((size_t)NB * TOPICS * VOCAB)

// ---------- bf16 helpers ----------
__device__ __forceinline__ float bf2f(u16 h) {
    union { u32 u; float f; } c; c.u = ((u32)h) << 16; return c.f;
}
__device__ __forceinline__ u16 f2bf(float f) {
    union { float f; u32 u; } c; c.f = f;
    u32 r = c.u + 0x7FFFu + ((c.u >> 16) & 1u);   // RNE
    return (u16)(r >> 16);
}

// generic scalar load: element i of tensor p, as float
template<bool F32>
__device__ __forceinline__ float ldv(const void* p, size_t i) {
    if constexpr (F32) return ((const float*)p)[i];
    else return bf2f(((const u16*)p)[i]);
}

// ---------- dtype detector ----------
// beta ~ N(0,1). If stored bf16, the LOW u16 of each u32 word is a bf16 value
// with exponent field in [110,132] (P~1). If stored fp32, the low u16 is raw
// mantissa bits -> exponent field uniform (P~9%). Count over 1024 words.
__global__ __launch_bounds__(64)
void k_detect(const u32* __restrict__ braw, int* __restrict__ flag) {
    int lane = threadIdx.x;
    int cnt = 0;
    for (int i = lane; i < 1024; i += 64) {
        u32 w = braw[i];
        u32 e = (w >> 7) & 0xFFu;          // low-half bf16 exponent field
        if (e >= 110u && e <= 132u) cnt++;
    }
    for (int off = 32; off; off >>= 1) cnt += __shfl_down(cnt, off, 64);
    if (lane == 0) flag[0] = (cnt < 512) ? 1 : 0;   // 1 = fp32, 0 = bf16
}

// ---------- threefry2x32-20, key (0, 42), partitionable counts (0, i) ----------
__device__ __forceinline__ u32 threefry_bits_partitionable(u32 i) {
    const u32 ks0 = 0u, ks1 = 42u, ks2 = 0u ^ 42u ^ 0x1BD11BDAu;
    u32 x0 = 0u + ks0, x1 = i + ks1;
#define TF_R(r) { x0 += x1; x1 = (x1 << r) | (x1 >> (32 - r)); x1 ^= x0; }
    TF_R(13) TF_R(15) TF_R(26) TF_R(6)
    x0 += ks1; x1 += ks2 + 1u;
    TF_R(17) TF_R(29) TF_R(16) TF_R(24)
    x0 += ks2; x1 += ks0 + 2u;
    TF_R(13) TF_R(15) TF_R(26) TF_R(6)
    x0 += ks0; x1 += ks1 + 3u;
    TF_R(17) TF_R(29) TF_R(16) TF_R(24)
    x0 += ks1; x1 += ks2 + 4u;
    TF_R(13) TF_R(15) TF_R(26) TF_R(6)
    x0 += ks2; x1 += ks0 + 5u;
#undef TF_R
    return x0 ^ x1;
}

// ---------- A: next_state ----------
template<bool F32>
__device__ void state_body(const void* xin, const void* h0, const void* Wxh,
                           const void* Whh, float* ns_f32, u16* ns_b16, void* dout) {
    __shared__ float lx[DIN + UNITS];
    int b = blockIdx.x >> 2;
    int u = ((blockIdx.x & 3) << 8) | threadIdx.x;
    for (int i = threadIdx.x; i < DIN; i += 256)
        lx[i] = ldv<F32>(xin, (size_t)b * DIN + i);
    for (int i = threadIdx.x; i < UNITS; i += 256)
        lx[DIN + i] = ldv<F32>(h0, (size_t)b * UNITS + i);
    __syncthreads();
    float acc = 0.f;
#pragma unroll 8
    for (int k = 0; k < DIN; ++k)   acc += lx[k]       * ldv<F32>(Wxh, (size_t)k * UNITS + u);
#pragma unroll 8
    for (int k = 0; k < UNITS; ++k) acc += lx[DIN + k] * ldv<F32>(Whh, (size_t)k * UNITS + u);
    int idx = b * UNITS + u;
    ns_f32[idx] = acc;
    ns_b16[idx] = f2bf(acc);
    if constexpr (F32) ((float*)dout)[NS_OFF + idx] = acc;
    else               ((u16*)dout)[NS_OFF + idx]   = f2bf(acc);
}

__global__ __launch_bounds__(256)
void k_state(const int* __restrict__ flag, const void* xin, const void* h0,
             const void* Wxh, const void* Whh,
             float* __restrict__ ns_f32, u16* __restrict__ ns_b16, void* dout) {
    if (*flag) state_body<true>(xin, h0, Wxh, Whh, ns_f32, ns_b16, dout);
    else       state_body<false>(xin, h0, Wxh, Whh, ns_f32, ns_b16, dout);
}

// ---------- B: bernoulli coefficient c_b = 1 - sample_b ----------
template<bool F32>
__device__ void bern_body(const float* ns, const void* bk, float* coeff) {
    int b = blockIdx.x;
    int lane = threadIdx.x;
    float s = 0.f;
#pragma unroll
    for (int i = 0; i < UNITS / 64; ++i) {
        int k = lane + (i << 6);
        s += ns[b * UNITS + k] * ldv<F32>(bk, k);
    }
    for (int off = 32; off; off >>= 1) s += __shfl_down(s, off, 64);
    if (lane == 0) {
        float z  = s;
        float sp = log1pf(expf(z));              // softplus
        float p  = 1.f / (1.f + expf(-sp));      // sigmoid
        u32 bits = threefry_bits_partitionable((u32)b);
        union { u32 u; float f; } c; c.u = (bits >> 9) | 0x3f800000u;
        float uni = c.f - 1.0f;                  // uniform [0,1)
        coeff[b] = (uni < p) ? 0.f : 1.f;        // (1 - bernoulli_sample)
    }
}

__global__ __launch_bounds__(64)
void k_bern(const int* __restrict__ flag, const float* __restrict__ ns,
            const void* bk, float* __restrict__ coeff) {
    if (*flag) bern_body<true>(ns, bk, coeff);
    else       bern_body<false>(ns, bk, coeff);
}

// ---------- C: sv[b][v] = ns[b][:] @ Wv[:, v] ----------
// ns always staged as our own bf16 copy (64 KiB LDS); Wv loads branch on dtype.
template<bool F32>
__device__ void sv_body(const u16* nsb, const void* Wv, float* sv) {
    __shared__ u16 lns[32 * UNITS];              // 64 KiB
    int vt = threadIdx.x & 63;
    int bg = threadIdx.x >> 6;
    int v0 = blockIdx.x * 256 + vt * 4;
    int bb = blockIdx.y * 32;

    {   // stage 32 bf16 ns rows into LDS
        const uint2* src = (const uint2*)(nsb + bb * UNITS);
        uint2* dst = (uint2*)lns;
        for (int i = threadIdx.x; i < (32 * UNITS) / 4; i += 256) dst[i] = src[i];
    }
    __syncthreads();

    float acc[8][4];
#pragma unroll
    for (int b = 0; b < 8; ++b)
#pragma unroll
        for (int j = 0; j < 4; ++j) acc[b][j] = 0.f;

    const u16* lrow = lns + (bg * 8) * UNITS;
    for (int u = 0; u < UNITS; u += 2) {
        float f00, f01, f02, f03, f10, f11, f12, f13;
        if constexpr (F32) {
            const float* base = (const float*)Wv + v0;
            float4 w0 = *(const float4*)(base + (size_t)u * VOCAB);
            float4 w1 = *(const float4*)(base + (size_t)(u + 1) * VOCAB);
            f00 = w0.x; f01 = w0.y; f02 = w0.z; f03 = w0.w;
            f10 = w1.x; f11 = w1.y; f12 = w1.z; f13 = w1.w;
        } else {
            const u16* base = (const u16*)Wv + v0;
            ushort4 w0 = *(const ushort4*)(base + (size_t)u * VOCAB);
            ushort4 w1 = *(const ushort4*)(base + (size_t)(u + 1) * VOCAB);
            f00 = bf2f(w0.x); f01 = bf2f(w0.y); f02 = bf2f(w0.z); f03 = bf2f(w0.w);
            f10 = bf2f(w1.x); f11 = bf2f(w1.y); f12 = bf2f(w1.z); f13 = bf2f(w1.w);
        }
#pragma unroll
        for (int b = 0; b < 8; ++b) {
            u32 pair = *(const u32*)(lrow + b * UNITS + u);   // 2 bf16, LDS broadcast
            float a0 = bf2f((u16)(pair & 0xFFFFu));
            float a1 = bf2f((u16)(pair >> 16));
            acc[b][0] += a0 * f00 + a1 * f10;
            acc[b][1] += a0 * f01 + a1 * f11;
            acc[b][2] += a0 * f02 + a1 * f12;
            acc[b][3] += a0 * f03 + a1 * f13;
        }
    }
#pragma unroll
    for (int b = 0; b < 8; ++b) {
        float4 o = {acc[b][0], acc[b][1], acc[b][2], acc[b][3]};
        *(float4*)(sv + (size_t)(bb + bg * 8 + b) * VOCAB + v0) = o;
    }
}

__global__ __launch_bounds__(256)
void k_sv(const int* __restrict__ flag, const u16* __restrict__ nsb,
          const void* Wv, float* __restrict__ sv) {
    if (*flag) sv_body<true>(nsb, Wv, sv);
    else       sv_body<false>(nsb, Wv, sv);
}

// ---------- D1: l[b][t] = sum_v exp(sv[b][v] + c_b * beta[t][v]) ----------
template<bool F32>
__device__ void sum_body(const float* sv, const void* beta, const float* coeff,
                         float* lsum) {
    int t = blockIdx.x, b = blockIdx.y;
    float c = coeff[b];
    const float* svr = sv + (size_t)b * VOCAB;
    int tid = threadIdx.x;
    float s = 0.f;
    for (int i = 0; i < 31; ++i) {               // 31 * 1024 = 31744 elems
        int v = (i * 256 + tid) * 4;
        float4 sval = *(const float4*)(svr + v);
        float b0, b1, b2, b3;
        if constexpr (F32) {
            float4 bv = *(const float4*)((const float*)beta + (size_t)t * VOCAB + v);
            b0 = bv.x; b1 = bv.y; b2 = bv.z; b3 = bv.w;
        } else {
            ushort4 bv = *(const ushort4*)((const u16*)beta + (size_t)t * VOCAB + v);
            b0 = bf2f(bv.x); b1 = bf2f(bv.y); b2 = bf2f(bv.z); b3 = bf2f(bv.w);
        }
        s += __expf(fmaf(c, b0, sval.x));
        s += __expf(fmaf(c, b1, sval.y));
        s += __expf(fmaf(c, b2, sval.z));
        s += __expf(fmaf(c, b3, sval.w));
    }
    {   // tail: 256 elems
        int v = 31744 + tid;
        s += __expf(fmaf(c, ldv<F32>(beta, (size_t)t * VOCAB + v), svr[v]));
    }
    __shared__ float red[4];
    for (int off = 32; off; off >>= 1) s += __shfl_down(s, off, 64);
    int lane = tid & 63, w = tid >> 6;
    if (lane == 0) red[w] = s;
    __syncthreads();
    if (tid == 0) lsum[b * TOPICS + t] = red[0] + red[1] + red[2] + red[3];
}

__global__ __launch_bounds__(256)
void k_sum(const int* __restrict__ flag, const float* __restrict__ sv,
           const void* beta, const float* __restrict__ coeff,
           float* __restrict__ lsum) {
    if (*flag) sum_body<true>(sv, beta, coeff, lsum);
    else       sum_body<false>(sv, beta, coeff, lsum);
}

// ---------- D2: word_prob = exp(sv + c*beta) / l ----------
template<bool F32>
__device__ void write_body(const float* sv, const void* beta, const float* coeff,
                           const float* lsum, void* dout) {
    int gid = blockIdx.x * 256 + threadIdx.x;    // 0 .. 255999
    int b  = gid / 4000;
    int v0 = (gid - b * 4000) * 8;
    float c = coeff[b];
    const float* svr = sv + (size_t)b * VOCAB + v0;
    float4 s0 = *(const float4*)(svr);
    float4 s1 = *(const float4*)(svr + 4);
#pragma unroll 4
    for (int t = 0; t < TOPICS; ++t) {
        float inv = 1.0f / lsum[b * TOPICS + t];
        float e0, e1, e2, e3, e4, e5, e6, e7;
        size_t boff = (size_t)t * VOCAB + v0;
        if constexpr (F32) {
            float4 b0 = *(const float4*)((const float*)beta + boff);
            float4 b1 = *(const float4*)((const float*)beta + boff + 4);
            e0 = __expf(fmaf(c, b0.x, s0.x)) * inv;
            e1 = __expf(fmaf(c, b0.y, s0.y)) * inv;
            e2 = __expf(fmaf(c, b0.z, s0.z)) * inv;
            e3 = __expf(fmaf(c, b0.w, s0.w)) * inv;
            e4 = __expf(fmaf(c, b1.x, s1.x)) * inv;
            e5 = __expf(fmaf(c, b1.y, s1.y)) * inv;
            e6 = __expf(fmaf(c, b1.z, s1.z)) * inv;
            e7 = __expf(fmaf(c, b1.w, s1.w)) * inv;
        } else {
            ushort4 b0 = *(const ushort4*)((const u16*)beta + boff);
            ushort4 b1 = *(const ushort4*)((const u16*)beta + boff + 4);
            e0 = __expf(fmaf(c, bf2f(b0.x), s0.x)) * inv;
            e1 = __expf(fmaf(c, bf2f(b0.y), s0.y)) * inv;
            e2 = __expf(fmaf(c, bf2f(b0.z), s0.z)) * inv;
            e3 = __expf(fmaf(c, bf2f(b0.w), s0.w)) * inv;
            e4 = __expf(fmaf(c, bf2f(b1.x), s1.x)) * inv;
            e5 = __expf(fmaf(c, bf2f(b1.y), s1.y)) * inv;
            e6 = __expf(fmaf(c, bf2f(b1.z), s1.z)) * inv;
            e7 = __expf(fmaf(c, bf2f(b1.w), s1.w)) * inv;
        }
        size_t ooff = (size_t)b * TOPICS * VOCAB + (size_t)t * VOCAB + v0;
        if constexpr (F32) {
            float4 o0 = {e0, e1, e2, e3};
            float4 o1 = {e4, e5, e6, e7};
            *(float4*)((float*)dout + ooff)     = o0;
            *(float4*)((float*)dout + ooff + 4) = o1;
        } else {
            uint4 st;
            st.x = (u32)f2bf(e0) | ((u32)f2bf(e1) << 16);
            st.y = (u32)f2bf(e2) | ((u32)f2bf(e3) << 16);
            st.z = (u32)f2bf(e4) | ((u32)f2bf(e5) << 16);
            st.w = (u32)f2bf(e6) | ((u32)f2bf(e7) << 16);
            *(uint4*)((u16*)dout + ooff) = st;
        }
    }
}

__global__ __launch_bounds__(256)
void k_write(const int* __restrict__ flag, const float* __restrict__ sv,
             const void* beta, const float* __restrict__ coeff,
             const float* __restrict__ lsum, void* dout) {
    if (*flag) write_body<true>(sv, beta, coeff, lsum, dout);
    else       write_body<false>(sv, beta, coeff, lsum, dout);
}

extern "C" void kernel_launch(void* const* d_in, const int* in_sizes, int n_in,
                              void* d_out, int out_size, void* d_ws, size_t ws_size,
                              hipStream_t stream) {
    const void* xin  = d_in[0];   // [64,512]
    const void* h0   = d_in[1];   // [64,1024]
    const void* Wxh  = d_in[2];   // [512,1024]
    const void* Whh  = d_in[3];   // [1024,1024]
    const void* bk   = d_in[4];   // [1024,1]
    const void* Wv   = d_in[5];   // [1024,32000]
    const void* beta = d_in[6];   // [20,32000]

    char* ws = (char*)d_ws;
    int*   flag   = (int*)  (ws + 0);
    float* coeff  = (float*)(ws + 256);
    float* lsum   = (float*)(ws + 512);       // 1280 floats -> ends 5632
    float* ns_f32 = (float*)(ws + 8192);      // 256 KiB -> ends 270336
    u16*   ns_b16 = (u16*)  (ws + 270336);    // 128 KiB -> ends 401408
    float* sv     = (float*)(ws + 401408);    // 8.192 MB -> ends 8593408

    k_detect<<<1, 64, 0, stream>>>((const u32*)beta, flag);
    k_state <<<256, 256, 0, stream>>>(flag, xin, h0, Wxh, Whh, ns_f32, ns_b16, d_out);
    k_bern  <<<64, 64, 0, stream>>>(flag, ns_f32, bk, coeff);
    k_sv    <<<dim3(125, 2), 256, 0, stream>>>(flag, ns_b16, Wv, sv);
    k_sum   <<<dim3(TOPICS, NB), 256, 0, stream>>>(flag, sv, beta, coeff, lsum);
    k_write <<<1000, 256, 0, stream>>>(flag, sv, beta, coeff, lsum, d_out);
}

// Round 3
// 470.482 us; speedup vs baseline: 1.2239x; 1.2239x over previous
//
#include <hip/hip_runtime.h>
#include <cstdint>
#include <cstddef>

typedef unsigned int u32;
typedef unsigned short u16;

#define NB 64
#define DIN 512
#define UNITS 1024
#define TOPICS 20
#define VOCAB 32000
#define NS_OFF ((size_t)NB * TOPICS * VOCAB)

// ---------- bf16 helpers ----------
__device__ __forceinline__ float bf2f(u16 h) {
    union { u32 u; float f; } c; c.u = ((u32)h) << 16; return c.f;
}
__device__ __forceinline__ u16 f2bf(float f) {
    union { float f; u32 u; } c; c.f = f;
    u32 r = c.u + 0x7FFFu + ((c.u >> 16) & 1u);   // RNE
    return (u16)(r >> 16);
}
template<bool F32>
__device__ __forceinline__ float ldv(const void* p, size_t i) {
    if constexpr (F32) return ((const float*)p)[i];
    else return bf2f(((const u16*)p)[i]);
}
__device__ __forceinline__ float ldr(const void* p, size_t i, bool f32) {
    return f32 ? ((const float*)p)[i] : bf2f(((const u16*)p)[i]);
}

// ---------- threefry2x32-20, key (0,42), partitionable counts (0,i) ----------
__device__ __forceinline__ u32 threefry_bits_partitionable(u32 i) {
    const u32 ks0 = 0u, ks1 = 42u, ks2 = 0u ^ 42u ^ 0x1BD11BDAu;
    u32 x0 = 0u + ks0, x1 = i + ks1;
#define TF_R(r) { x0 += x1; x1 = (x1 << r) | (x1 >> (32 - r)); x1 ^= x0; }
    TF_R(13) TF_R(15) TF_R(26) TF_R(6)
    x0 += ks1; x1 += ks2 + 1u;
    TF_R(17) TF_R(29) TF_R(16) TF_R(24)
    x0 += ks2; x1 += ks0 + 2u;
    TF_R(13) TF_R(15) TF_R(26) TF_R(6)
    x0 += ks0; x1 += ks1 + 3u;
    TF_R(17) TF_R(29) TF_R(16) TF_R(24)
    x0 += ks1; x1 += ks2 + 4u;
    TF_R(13) TF_R(15) TF_R(26) TF_R(6)
    x0 += ks2; x1 += ks0 + 5u;
#undef TF_R
    return x0 ^ x1;
}

// ---------- init: self-detect dtype, eb = exp(beta), zero lsum, publish flag ----------
// grid 320 x 256. Each block detects dtype locally on beta[0:1024] words
// (i.i.d. N(0,1): bf16 -> low-u16 exponent field in [110,132] w.p. ~1;
// fp32 -> ~9%), so no cross-block dependency.
__global__ __launch_bounds__(256)
void k_init(const void* __restrict__ beta, int* __restrict__ flag,
            float* __restrict__ lsum, float* __restrict__ eb) {
    int tid = threadIdx.x, lane = tid & 63, w = tid >> 6;
    __shared__ int cnt_s[4];
    int cnt = 0;
    const u32* braw = (const u32*)beta;
    for (int i = tid; i < 1024; i += 256) {
        u32 x = braw[i];
        u32 e = (x >> 7) & 0xFFu;
        cnt += (e >= 110u && e <= 132u) ? 1 : 0;
    }
    for (int off = 32; off; off >>= 1) cnt += __shfl_down(cnt, off, 64);
    if (lane == 0) cnt_s[w] = cnt;
    __syncthreads();
    int total = cnt_s[0] + cnt_s[1] + cnt_s[2] + cnt_s[3];
    bool f32 = total < 512;

    size_t base = (size_t)blockIdx.x * 2000;
    for (int i = tid; i < 2000; i += 256)
        eb[base + i] = __expf(ldr(beta, base + i, f32));

    if (blockIdx.x == 0) {
        for (int i = tid; i < NB * TOPICS; i += 256) lsum[i] = 0.f;
        if (tid == 0) flag[0] = f32 ? 1 : 0;
    }
}

// ---------- A: next_state = x@Wxh + h@Whh ----------
template<bool F32>
__device__ void state_body(const void* xin, const void* h0, const void* Wxh,
                           const void* Whh, float* ns_f32, void* dout) {
    __shared__ float lx[DIN + UNITS];
    int b = blockIdx.x >> 2;
    int u = ((blockIdx.x & 3) << 8) | threadIdx.x;
    for (int i = threadIdx.x; i < DIN; i += 256)
        lx[i] = ldv<F32>(xin, (size_t)b * DIN + i);
    for (int i = threadIdx.x; i < UNITS; i += 256)
        lx[DIN + i] = ldv<F32>(h0, (size_t)b * UNITS + i);
    __syncthreads();
    float acc = 0.f;
#pragma unroll 8
    for (int k = 0; k < DIN; ++k)   acc += lx[k]       * ldv<F32>(Wxh, (size_t)k * UNITS + u);
#pragma unroll 8
    for (int k = 0; k < UNITS; ++k) acc += lx[DIN + k] * ldv<F32>(Whh, (size_t)k * UNITS + u);
    int idx = b * UNITS + u;
    ns_f32[idx] = acc;
    if constexpr (F32) ((float*)dout)[NS_OFF + idx] = acc;
    else               ((u16*)dout)[NS_OFF + idx]   = f2bf(acc);
}
__global__ __launch_bounds__(256)
void k_state(const int* __restrict__ flag, const void* xin, const void* h0,
             const void* Wxh, const void* Whh,
             float* __restrict__ ns_f32, void* dout) {
    if (*flag) state_body<true>(xin, h0, Wxh, Whh, ns_f32, dout);
    else       state_body<false>(xin, h0, Wxh, Whh, ns_f32, dout);
}

// ---------- B: coeff_b = 1 - bernoulli_sample ----------
template<bool F32>
__device__ void bern_body(const float* ns, const void* bk, float* coeff) {
    int b = blockIdx.x, lane = threadIdx.x;
    float s = 0.f;
#pragma unroll
    for (int i = 0; i < UNITS / 64; ++i) {
        int k = lane + (i << 6);
        s += ns[b * UNITS + k] * ldv<F32>(bk, k);
    }
    for (int off = 32; off; off >>= 1) s += __shfl_down(s, off, 64);
    if (lane == 0) {
        float sp = log1pf(expf(s));              // softplus
        float p  = 1.f / (1.f + expf(-sp));      // sigmoid
        u32 bits = threefry_bits_partitionable((u32)b);
        union { u32 u; float f; } c; c.u = (bits >> 9) | 0x3f800000u;
        float uni = c.f - 1.0f;
        coeff[b] = (uni < p) ? 0.f : 1.f;        // (1 - sample)
    }
}
__global__ __launch_bounds__(64)
void k_bern(const int* __restrict__ flag, const float* __restrict__ ns,
            const void* bk, float* __restrict__ coeff) {
    if (*flag) bern_body<true>(ns, bk, coeff);
    else       bern_body<false>(ns, bk, coeff);
}

// ---------- C: esv[b][v] = exp( ns[b][:] @ Wv[:,v] )  (LDS-tiled GEMM) ----------
// grid 500 blocks (v-tile 64), 256 threads, full K=1024 in 16 chunks of 64.
// Thread tile 2b x 8v; A/B tiles padded to 68 floats/row (bank conflicts).
#define PAD 68
template<bool F32>
__device__ void sv_body(const float* __restrict__ ns, const void* __restrict__ Wv,
                        float* __restrict__ esv) {
    __shared__ float As[64 * PAD];
    __shared__ float Bs[64 * PAD];
    int tid = threadIdx.x;
    int vt = tid & 7;           // 8 v-threads x 8 v = 64 v
    int bg = tid >> 3;          // 32 groups x 2 b = 64 b
    int v0 = blockIdx.x * 64;
    float acc[2][8];
#pragma unroll
    for (int r = 0; r < 2; ++r)
#pragma unroll
        for (int j = 0; j < 8; ++j) acc[r][j] = 0.f;

    for (int k0 = 0; k0 < UNITS; k0 += 64) {
        __syncthreads();
        for (int e = tid; e < 1024; e += 256) {      // stage A: ns[64b][64k]
            int row = e >> 4, c4 = e & 15;
            *(float4*)&As[row * PAD + c4 * 4] =
                *(const float4*)&ns[row * UNITS + k0 + c4 * 4];
        }
        for (int e = tid; e < 1024; e += 256) {      // stage B: Wv[64k][64v]
            int row = e >> 4, c4 = e & 15;
            float4 wv;
            if constexpr (F32) {
                wv = *(const float4*)((const float*)Wv + (size_t)(k0 + row) * VOCAB + v0 + c4 * 4);
            } else {
                ushort4 t4 = *(const ushort4*)((const u16*)Wv + (size_t)(k0 + row) * VOCAB + v0 + c4 * 4);
                wv.x = bf2f(t4.x); wv.y = bf2f(t4.y); wv.z = bf2f(t4.z); wv.w = bf2f(t4.w);
            }
            *(float4*)&Bs[row * PAD + c4 * 4] = wv;
        }
        __syncthreads();
#pragma unroll 4
        for (int u = 0; u < 64; u += 4) {
            float4 a0 = *(float4*)&As[(bg * 2 + 0) * PAD + u];
            float4 a1 = *(float4*)&As[(bg * 2 + 1) * PAD + u];
            float aa0[4] = {a0.x, a0.y, a0.z, a0.w};
            float aa1[4] = {a1.x, a1.y, a1.z, a1.w};
#pragma unroll
            for (int uu = 0; uu < 4; ++uu) {
                float4 b0 = *(float4*)&Bs[(u + uu) * PAD + vt * 8];
                float4 b1 = *(float4*)&Bs[(u + uu) * PAD + vt * 8 + 4];
                float bb[8] = {b0.x, b0.y, b0.z, b0.w, b1.x, b1.y, b1.z, b1.w};
#pragma unroll
                for (int j = 0; j < 8; ++j) {
                    acc[0][j] = fmaf(aa0[uu], bb[j], acc[0][j]);
                    acc[1][j] = fmaf(aa1[uu], bb[j], acc[1][j]);
                }
            }
        }
    }
#pragma unroll
    for (int r = 0; r < 2; ++r) {
        float4 e0, e1;
        e0.x = __expf(acc[r][0]); e0.y = __expf(acc[r][1]);
        e0.z = __expf(acc[r][2]); e0.w = __expf(acc[r][3]);
        e1.x = __expf(acc[r][4]); e1.y = __expf(acc[r][5]);
        e1.z = __expf(acc[r][6]); e1.w = __expf(acc[r][7]);
        float* dst = esv + (size_t)(bg * 2 + r) * VOCAB + v0 + vt * 8;
        *(float4*)dst = e0;
        *(float4*)(dst + 4) = e1;
    }
}
__global__ __launch_bounds__(256)
void k_sv(const int* __restrict__ flag, const float* __restrict__ ns,
          const void* Wv, float* __restrict__ esv) {
    if (*flag) sv_body<true>(ns, Wv, esv);
    else       sv_body<false>(ns, Wv, esv);
}

// ---------- D1: lsum[b][t] = sum_v esv[b][v] * (c ? eb[t][v] : 1) ----------
// grid (16 vc, 64 b) x 256. Reads esv once; 20 register accumulators.
__global__ __launch_bounds__(256)
void k_sum(const float* __restrict__ esv, const float* __restrict__ eb,
           const float* __restrict__ coeff, float* __restrict__ lsum) {
    int b = blockIdx.y, tid = threadIdx.x;
    float c = coeff[b];
    const float4* e4 = (const float4*)(esv + (size_t)b * VOCAB);
    int i0 = blockIdx.x * 256 + tid;
    __shared__ float red[4][TOPICS];
    int lane = tid & 63, w = tid >> 6;

    if (c != 0.f) {
        float acc[TOPICS];
#pragma unroll
        for (int t = 0; t < TOPICS; ++t) acc[t] = 0.f;
        for (int i = i0; i < VOCAB / 4; i += 4096) {
            float4 e = e4[i];
#pragma unroll
            for (int t = 0; t < TOPICS; ++t) {
                float4 g = *(const float4*)(eb + (size_t)t * VOCAB + i * 4);
                acc[t] += e.x * g.x + e.y * g.y + e.z * g.z + e.w * g.w;
            }
        }
#pragma unroll
        for (int t = 0; t < TOPICS; ++t) {
            float v = acc[t];
            for (int off = 32; off; off >>= 1) v += __shfl_down(v, off, 64);
            if (lane == 0) red[w][t] = v;
        }
        __syncthreads();
        if (tid < TOPICS) {
            float s = red[0][tid] + red[1][tid] + red[2][tid] + red[3][tid];
            atomicAdd(&lsum[b * TOPICS + tid], s);
        }
    } else {
        float a = 0.f;
        for (int i = i0; i < VOCAB / 4; i += 4096) {
            float4 e = e4[i];
            a += e.x + e.y + e.z + e.w;
        }
        for (int off = 32; off; off >>= 1) a += __shfl_down(a, off, 64);
        if (lane == 0) red[w][0] = a;
        __syncthreads();
        if (tid < TOPICS) {
            float s = red[0][0] + red[1][0] + red[2][0] + red[3][0];
            atomicAdd(&lsum[b * TOPICS + tid], s);
        }
    }
}

// ---------- D2: out[b][t][v] = esv[b][v] * (c ? eb[t][v] : 1) / lsum[b][t] ----------
// grid (16 vc, 64 b) x 256, thread = 8 v, loops 20 topics; pure write-bound.
template<bool F32>
__device__ void write_body(const float* esv, const float* eb, const float* coeff,
                           const float* lsum, void* dout) {
    int b = blockIdx.y, tid = threadIdx.x;
    int v0 = blockIdx.x * 2048 + tid * 8;
    if (v0 >= VOCAB) return;
    float c = coeff[b];
    const float* er = esv + (size_t)b * VOCAB + v0;
    float4 e0 = *(const float4*)er;
    float4 e1 = *(const float4*)(er + 4);
#pragma unroll 4
    for (int t = 0; t < TOPICS; ++t) {
        float inv = 1.0f / lsum[b * TOPICS + t];
        float o0, o1, o2, o3, o4, o5, o6, o7;
        if (c != 0.f) {
            const float* gr = eb + (size_t)t * VOCAB + v0;
            float4 g0 = *(const float4*)gr;
            float4 g1 = *(const float4*)(gr + 4);
            o0 = e0.x * g0.x * inv; o1 = e0.y * g0.y * inv;
            o2 = e0.z * g0.z * inv; o3 = e0.w * g0.w * inv;
            o4 = e1.x * g1.x * inv; o5 = e1.y * g1.y * inv;
            o6 = e1.z * g1.z * inv; o7 = e1.w * g1.w * inv;
        } else {
            o0 = e0.x * inv; o1 = e0.y * inv; o2 = e0.z * inv; o3 = e0.w * inv;
            o4 = e1.x * inv; o5 = e1.y * inv; o6 = e1.z * inv; o7 = e1.w * inv;
        }
        size_t off = (size_t)b * TOPICS * VOCAB + (size_t)t * VOCAB + v0;
        if constexpr (F32) {
            float4 s0 = {o0, o1, o2, o3}, s1 = {o4, o5, o6, o7};
            *(float4*)((float*)dout + off) = s0;
            *(float4*)((float*)dout + off + 4) = s1;
        } else {
            uint4 st;
            st.x = (u32)f2bf(o0) | ((u32)f2bf(o1) << 16);
            st.y = (u32)f2bf(o2) | ((u32)f2bf(o3) << 16);
            st.z = (u32)f2bf(o4) | ((u32)f2bf(o5) << 16);
            st.w = (u32)f2bf(o6) | ((u32)f2bf(o7) << 16);
            *(uint4*)((u16*)dout + off) = st;
        }
    }
}
__global__ __launch_bounds__(256)
void k_write(const int* __restrict__ flag, const float* __restrict__ esv,
             const float* __restrict__ eb, const float* __restrict__ coeff,
             const float* __restrict__ lsum, void* dout) {
    if (*flag) write_body<true>(esv, eb, coeff, lsum, dout);
    else       write_body<false>(esv, eb, coeff, lsum, dout);
}

extern "C" void kernel_launch(void* const* d_in, const int* in_sizes, int n_in,
                              void* d_out, int out_size, void* d_ws, size_t ws_size,
                              hipStream_t stream) {
    const void* xin  = d_in[0];
    const void* h0   = d_in[1];
    const void* Wxh  = d_in[2];
    const void* Whh  = d_in[3];
    const void* bk   = d_in[4];
    const void* Wv   = d_in[5];
    const void* beta = d_in[6];

    char* ws = (char*)d_ws;
    int*   flag   = (int*)  (ws + 0);
    float* coeff  = (float*)(ws + 256);
    float* lsum   = (float*)(ws + 1024);      // 1280 f -> ends 6144
    float* ns_f32 = (float*)(ws + 8192);      // 256 KiB -> ends 270336
    float* eb     = (float*)(ws + 270336);    // 2.56 MB -> ends 2830336
    float* esv    = (float*)(ws + 2830336);   // 8.192 MB -> ends 11022336

    k_init <<<320, 256, 0, stream>>>(beta, flag, lsum, eb);
    k_state<<<256, 256, 0, stream>>>(flag, xin, h0, Wxh, Whh, ns_f32, d_out);
    k_bern <<<64, 64, 0, stream>>>(flag, ns_f32, bk, coeff);
    k_sv   <<<500, 256, 0, stream>>>(flag, ns_f32, Wv, esv);
    k_sum  <<<dim3(16, 64), 256, 0, stream>>>(esv, eb, coeff, lsum);
    k_write<<<dim3(16, 64), 256, 0, stream>>>(flag, esv, eb, coeff, lsum, d_out);
}